// Round 8
// baseline (675.410 us; speedup 1.0000x reference)
//
#include <hip/hip_runtime.h>

#define DM     1024
#define DFF    4096
#define NE     8
#define TT     8192
#define CAP    8192
#define RTOK   32
#define MAXRA  17664

typedef __bf16 bf16x8 __attribute__((ext_vector_type(8)));
typedef float  f32x16 __attribute__((ext_vector_type(16)));
typedef unsigned short u16;
typedef unsigned int   u32;

__device__ __forceinline__ u16 f2bf(float f) {
    u32 u = __builtin_bit_cast(u32, f);
    u += 0x7fffu + ((u >> 16) & 1u);   // round-to-nearest-even
    return (u16)(u >> 16);
}

__device__ __forceinline__ void gload_lds16(const void* g, void* l) {
    __builtin_amdgcn_global_load_lds(
        (const __attribute__((address_space(1))) void*)g,
        (__attribute__((address_space(3))) void*)l,
        16, 0, 0);
}

// ---------------- router: block-aggregated top-2 routing ----------------
__global__ __launch_bounds__(256) void router_k(
    const float* __restrict__ x, const float* __restrict__ Wr, const float* __restrict__ br,
    int* __restrict__ expert_count, float* __restrict__ prob_sum,
    int* __restrict__ list_token, float* __restrict__ list_w,
    int* __restrict__ tok_e, int* __restrict__ tok_q, float* __restrict__ tok_w)
{
    __shared__ float wrT[NE][DM];
    __shared__ float ps[NE];
    __shared__ int   lcount[NE];
    __shared__ int   lbase[NE];
    __shared__ int   lexp[RTOK * 2];
    __shared__ float lw[RTOK * 2];
    __shared__ int   lslot[RTOK * 2];

    int tid = threadIdx.x;
    if (tid < NE) { ps[tid] = 0.f; lcount[tid] = 0; }
#pragma unroll
    for (int it = 0; it < 8; ++it) {
        int f = tid * 4 + it * 1024;
        float4 v = *reinterpret_cast<const float4*>(Wr + f);
        int e0 = f & 7, k = f >> 3;
        wrT[e0][k] = v.x; wrT[e0 + 1][k] = v.y; wrT[e0 + 2][k] = v.z; wrT[e0 + 3][k] = v.w;
    }
    __syncthreads();

    int w = tid >> 6, l = tid & 63;
    for (int j = 0; j < RTOK / 4; ++j) {
        int ti = w * (RTOK / 4) + j;
        int token = blockIdx.x * RTOK + ti;
        const float* xr = x + (size_t)token * DM;
        float acc[NE];
#pragma unroll
        for (int e = 0; e < NE; ++e) acc[e] = 0.f;
#pragma unroll
        for (int i = 0; i < 4; ++i) {
            float4 xv = *reinterpret_cast<const float4*>(xr + i * 256 + l * 4);
#pragma unroll
            for (int e = 0; e < NE; ++e) {
                float4 wv = *reinterpret_cast<const float4*>(&wrT[e][i * 256 + l * 4]);
                acc[e] += xv.x * wv.x + xv.y * wv.y + xv.z * wv.z + xv.w * wv.w;
            }
        }
#pragma unroll
        for (int off = 32; off >= 1; off >>= 1) {
#pragma unroll
            for (int e = 0; e < NE; ++e) acc[e] += __shfl_xor(acc[e], off);
        }
        if (l == 0) {
            float li[NE], m = -1e30f;
#pragma unroll
            for (int e = 0; e < NE; ++e) { li[e] = (acc[e] + br[e]) * (1.0f / 0.7f); m = fmaxf(m, li[e]); }
            float p[NE], s = 0.f;
#pragma unroll
            for (int e = 0; e < NE; ++e) { p[e] = __expf(li[e] - m); s += p[e]; }
            float inv = 1.f / s;
#pragma unroll
            for (int e = 0; e < NE; ++e) { p[e] *= inv; atomicAdd(&ps[e], p[e]); }
            float v1 = -1.f, v2 = -1.f; int e1 = 0, e2 = 0;
#pragma unroll
            for (int e = 0; e < NE; ++e) {   // ascending scan: ties keep lower index (top_k semantics)
                float pe = p[e];
                if (pe > v1)      { v2 = v1; e2 = e1; v1 = pe; e1 = e; }
                else if (pe > v2) { v2 = pe; e2 = e; }
            }
            float denom = v1 + v2 + 1e-6f;
            lexp[2 * ti]     = e1; lw[2 * ti]     = v1 / denom; lslot[2 * ti]     = atomicAdd(&lcount[e1], 1);
            lexp[2 * ti + 1] = e2; lw[2 * ti + 1] = v2 / denom; lslot[2 * ti + 1] = atomicAdd(&lcount[e2], 1);
        }
    }
    __syncthreads();
    if (tid < NE) {
        lbase[tid] = atomicAdd(&expert_count[tid], lcount[tid]);
        atomicAdd(&prob_sum[tid], ps[tid]);
    }
    __syncthreads();
    if (tid < RTOK * 2) {
        int e = lexp[tid];
        int q = lbase[e] + lslot[tid];
        int token = blockIdx.x * RTOK + (tid >> 1);
        list_token[e * CAP + q] = token;
        list_w[e * CAP + q] = lw[tid];
        int slot = token * 2 + (tid & 1);
        tok_e[slot] = e; tok_q[slot] = q; tok_w[slot] = lw[tid];
    }
}

// ---------------- scan: padded offsets (to 128) + aux loss ----------------
__global__ void scan_aux_k(const int* __restrict__ expert_count, const float* __restrict__ prob_sum,
                           int* __restrict__ padded_count, int* __restrict__ poffsets,
                           float* __restrict__ aux_out)
{
    if (threadIdx.x == 0 && blockIdx.x == 0) {
        int off = 0; float aux = 0.f;
        for (int e = 0; e < NE; ++e) {
            int c = expert_count[e];
            int pc = (c + 127) / 128 * 128;
            poffsets[e] = off; padded_count[e] = pc; off += pc;
            aux += ((float)c / (float)TT) * (prob_sum[e] / (float)TT);
        }
        aux_out[0] = aux * (float)NE;
    }
}

// ---------------- gather routed x rows -> bf16 Xg ----------------
__global__ __launch_bounds__(256) void gather_k(
    const float* __restrict__ x, const int* __restrict__ list_token,
    const int* __restrict__ expert_count, const int* __restrict__ padded_count,
    const int* __restrict__ poffsets, u16* __restrict__ Xg)
{
    int e = blockIdx.y;
    int p0 = blockIdx.x * 8;
    if (p0 >= padded_count[e]) return;
    int tid = threadIdx.x;
    int rr = tid >> 5, cl = tid & 31;
    int p = p0 + rr;
    int g = poffsets[e] + p;
    u16* dst = Xg + (size_t)g * DM;
    bool valid = p < expert_count[e];
    int tok = valid ? list_token[e * CAP + p] : 0;
    const float* src = x + (size_t)tok * DM;
#pragma unroll
    for (int i = 0; i < 4; ++i) {
        int c0 = cl * 8 + i * 256;
        uint4 v;
        if (valid) {
            float4 f0 = *reinterpret_cast<const float4*>(src + c0);
            float4 f1 = *reinterpret_cast<const float4*>(src + c0 + 4);
            v.x = f2bf(f0.x) | ((u32)f2bf(f0.y) << 16);
            v.y = f2bf(f0.z) | ((u32)f2bf(f0.w) << 16);
            v.z = f2bf(f1.x) | ((u32)f2bf(f1.y) << 16);
            v.w = f2bf(f1.z) | ((u32)f2bf(f1.w) << 16);
        } else {
            v.x = 0; v.y = 0; v.z = 0; v.w = 0;
        }
        *reinterpret_cast<uint4*>(dst + c0) = v;
    }
}

// ---------------- transpose + fp32->bf16: src[e][k*rs + j] -> dst[e][j*Ktot + k] ----------------
__global__ __launch_bounds__(256) void convt_k(
    const float* __restrict__ src, u16* __restrict__ dst, int rs, int Ktot, long dstEStride)
{
    __shared__ float tile[64][65];
    int e = blockIdx.z;
    int k0 = blockIdx.x * 64, j0 = blockIdx.y * 64;
    const float* s = src + (size_t)e * 4194304;
    int tid = threadIdx.x;
    {
        int jj = (tid & 15) * 4, kb = tid >> 4;
#pragma unroll
        for (int i = 0; i < 4; ++i) {
            int k = kb + i * 16;
            float4 v = *reinterpret_cast<const float4*>(s + (size_t)(k0 + k) * rs + j0 + jj);
            tile[k][jj] = v.x; tile[k][jj + 1] = v.y; tile[k][jj + 2] = v.z; tile[k][jj + 3] = v.w;
        }
    }
    __syncthreads();
    {
        int kk = (tid & 15) * 4, jb = tid >> 4;
        u16* d = dst + (size_t)e * dstEStride;
#pragma unroll
        for (int i = 0; i < 4; ++i) {
            int j = jb + i * 16;
            uint2 q;
            q.x = f2bf(tile[kk][j])     | ((u32)f2bf(tile[kk + 1][j]) << 16);
            q.y = f2bf(tile[kk + 2][j]) | ((u32)f2bf(tile[kk + 3][j]) << 16);
            *reinterpret_cast<uint2*>(d + (size_t)(j0 + j) * Ktot + k0 + kk) = q;
        }
    }
}

// ====== 256x128 GEMM, v_mfma_f32_32x32x16_bf16, 4 waves (2M x 2N), wave-tile 128x64 ======
// 2x FLOP per ds_read_b128 vs 16x16x32 (LDS-read-bound fix). Proven 2-barrier K-loop,
// gload_lds w16 staging, chunk-swizzle involution slot = row*8 + (c8 ^ (row&7)).
// A frag: row=lane&31, k=(lane>>5)*8+e ; B frag: col=lane&31, same k-map (k-perm-invariant).
// C/D: col=lane&31, row=(reg&3)+8*(reg>>2)+4*(lane>>5)  [m74/m101].

__device__ __forceinline__ f32x16 mfma32(bf16x8 a, bf16x8 b, f32x16 c) {
    return __builtin_amdgcn_mfma_f32_32x32x16_bf16(a, b, c, 0, 0, 0);
}

// A: 256 rows stride lda; B: 128 n-rows stride ldb ([N][K]). LDS: A 32KB @0, B 16KB @32768.
__device__ __forceinline__ void gemm_main32(
    const u16* __restrict__ A, long lda, const u16* __restrict__ B, long ldb,
    int nkt, char* smem, f32x16 acc[4][2])
{
    int tid = threadIdx.x;
    int l = tid & 63, l31 = l & 31, kg = l >> 5;
    int wid = tid >> 6, wm = wid >> 1, wn = wid & 1;
    char* bufA = smem;
    char* bufB = smem + 32768;

    for (int kt = 0; kt < nkt; ++kt) {
        // stage A tile 256x64 (8 instr) + B tile 128x64 (4 instr), pre-swizzled source
#pragma unroll
        for (int i = 0; i < 8; ++i) {
            int sbase = i * 256 + wid * 64;
            int sl = sbase + l;
            int row = sl >> 3;
            int c8 = (sl & 7) ^ (row & 7);
            gload_lds16(A + (size_t)row * lda + kt * 64 + c8 * 8, bufA + sbase * 16);
        }
#pragma unroll
        for (int i = 0; i < 4; ++i) {
            int sbase = i * 256 + wid * 64;
            int sl = sbase + l;
            int row = sl >> 3;
            int c8 = (sl & 7) ^ (row & 7);
            gload_lds16(B + (size_t)row * ldb + kt * 64 + c8 * 8, bufB + sbase * 16);
        }
        __syncthreads();
#pragma unroll
        for (int ks = 0; ks < 4; ++ks) {
            bf16x8 af[4], bb[2];
#pragma unroll
            for (int mi = 0; mi < 4; ++mi) {
                int row = wm * 128 + mi * 32 + l31;
                int ch = (ks * 2 + kg) ^ (row & 7);
                af[mi] = *reinterpret_cast<const bf16x8*>(bufA + (row * 8 + ch) * 16);
            }
#pragma unroll
            for (int ni = 0; ni < 2; ++ni) {
                int row = wn * 64 + ni * 32 + l31;
                int ch = (ks * 2 + kg) ^ (row & 7);
                bb[ni] = *reinterpret_cast<const bf16x8*>(bufB + (row * 8 + ch) * 16);
            }
#pragma unroll
            for (int mi = 0; mi < 4; ++mi)
#pragma unroll
                for (int ni = 0; ni < 2; ++ni)
                    acc[mi][ni] = mfma32(af[mi], bb[ni], acc[mi][ni]);
        }
        __syncthreads();
    }
}

// ---------------- GEMM1: H = silu(Xg @ W1c + b1), bf16, N=4096, K=1024 ----------------
__global__ __launch_bounds__(256, 2) void gemm1_k(
    const u16* __restrict__ Xg, const u16* __restrict__ W1c, const float* __restrict__ b1,
    const int* __restrict__ padded_count, const int* __restrict__ poffsets,
    u16* __restrict__ H)
{
    __shared__ char smem[49152];
    int cb = blockIdx.x, rb = blockIdx.y, e = blockIdx.z;
    int pc = padded_count[e];
    if (rb * 256 >= pc) return;
    int row0 = poffsets[e] + rb * 256;
    const u16* Arows = Xg + (size_t)row0 * 1024;
    const u16* Brows = W1c + (size_t)e * DFF * 1024 + (size_t)cb * 128 * 1024;
    f32x16 acc[4][2];
#pragma unroll
    for (int i = 0; i < 4; ++i)
#pragma unroll
        for (int j = 0; j < 2; ++j)
#pragma unroll
            for (int r = 0; r < 16; ++r) acc[i][j][r] = 0.f;
    gemm_main32(Arows, 1024, Brows, 1024, 16, smem, acc);

    int tid = threadIdx.x, l = tid & 63, l31 = l & 31, kg = l >> 5;
    int wid = tid >> 6, wm = wid >> 1, wn = wid & 1;
    const float* b1e = b1 + (size_t)e * DFF;
#pragma unroll
    for (int mi = 0; mi < 4; ++mi) {
#pragma unroll
        for (int ni = 0; ni < 2; ++ni) {
            int col = cb * 128 + wn * 64 + ni * 32 + l31;
            float bv = b1e[col];
#pragma unroll
            for (int reg = 0; reg < 16; ++reg) {
                int rl = wm * 128 + mi * 32 + (reg & 3) + 8 * (reg >> 2) + 4 * kg;
                int p = rb * 256 + rl;
                if (p < pc) {
                    float z = acc[mi][ni][reg] + bv;
                    float hval = z / (1.f + __expf(-z));
                    H[(size_t)(row0 + rl) * DFF + col] = f2bf(hval);
                }
            }
        }
    }
}

// ---------------- GEMM2: Og[row] = Hb @ W2c, fp32, N=1024, K=4096 ----------------
__global__ __launch_bounds__(256, 2) void gemm2_k(
    const u16* __restrict__ Hb, const u16* __restrict__ W2c,
    const int* __restrict__ padded_count, const int* __restrict__ poffsets,
    float* __restrict__ Og)
{
    __shared__ char smem[49152];
    int cb = blockIdx.x, rb = blockIdx.y, e = blockIdx.z;
    int pc = padded_count[e];
    if (rb * 256 >= pc) return;
    int row0 = poffsets[e] + rb * 256;
    const u16* Arows = Hb + (size_t)row0 * DFF;
    const u16* Brows = W2c + (size_t)e * DM * DFF + (size_t)cb * 128 * DFF;
    f32x16 acc[4][2];
#pragma unroll
    for (int i = 0; i < 4; ++i)
#pragma unroll
        for (int j = 0; j < 2; ++j)
#pragma unroll
            for (int r = 0; r < 16; ++r) acc[i][j][r] = 0.f;
    gemm_main32(Arows, DFF, Brows, DFF, 64, smem, acc);

    int tid = threadIdx.x, l = tid & 63, l31 = l & 31, kg = l >> 5;
    int wid = tid >> 6, wm = wid >> 1, wn = wid & 1;
#pragma unroll
    for (int mi = 0; mi < 4; ++mi) {
#pragma unroll
        for (int reg = 0; reg < 16; ++reg) {
            int rl = wm * 128 + mi * 32 + (reg & 3) + 8 * (reg >> 2) + 4 * kg;
            int p = rb * 256 + rl;
            if (p < pc) {
                float* orow = Og + (size_t)(row0 + rl) * DM;
#pragma unroll
                for (int ni = 0; ni < 2; ++ni) {
                    int col = cb * 128 + wn * 64 + ni * 32 + l31;
                    orow[col] = acc[mi][ni][reg];
                }
            }
        }
    }
}

// ---------------- combine: out[t] = sum_r w_r * (Og[row_r] + b2[e_r]) ----------------
__global__ __launch_bounds__(256) void combine_k(
    const float* __restrict__ Og, const float* __restrict__ b2,
    const int* __restrict__ tok_e, const int* __restrict__ tok_q, const float* __restrict__ tok_w,
    const int* __restrict__ poffsets, float* __restrict__ out)
{
    int t = blockIdx.x * 4 + (threadIdx.x >> 6);
    int l = threadIdx.x & 63;
    int e0 = tok_e[t * 2], q0 = tok_q[t * 2];
    int e1 = tok_e[t * 2 + 1], q1 = tok_q[t * 2 + 1];
    float w0 = tok_w[t * 2], w1 = tok_w[t * 2 + 1];
    const float* r0 = Og + (size_t)(poffsets[e0] + q0) * DM;
    const float* r1 = Og + (size_t)(poffsets[e1] + q1) * DM;
    const float* bb0 = b2 + (size_t)e0 * DM;
    const float* bb1 = b2 + (size_t)e1 * DM;
    float* o = out + (size_t)t * DM;
#pragma unroll
    for (int i = 0; i < 4; ++i) {
        int c = l * 4 + i * 256;
        float4 a = *reinterpret_cast<const float4*>(r0 + c);
        float4 b = *reinterpret_cast<const float4*>(r1 + c);
        float4 p = *reinterpret_cast<const float4*>(bb0 + c);
        float4 q = *reinterpret_cast<const float4*>(bb1 + c);
        float4 res;
        res.x = w0 * (a.x + p.x) + w1 * (b.x + q.x);
        res.y = w0 * (a.y + p.y) + w1 * (b.y + q.y);
        res.z = w0 * (a.z + p.z) + w1 * (b.z + q.z);
        res.w = w0 * (a.w + p.w) + w1 * (b.w + q.w);
        *reinterpret_cast<float4*>(o + c) = res;
    }
}

extern "C" void kernel_launch(void* const* d_in, const int* in_sizes, int n_in,
                              void* d_out, int out_size, void* d_ws, size_t ws_size,
                              hipStream_t stream) {
    (void)in_sizes; (void)n_in; (void)out_size; (void)ws_size;
    const float* x  = (const float*)d_in[0];
    const float* Wr = (const float*)d_in[1];
    const float* br = (const float*)d_in[2];
    const float* W1 = (const float*)d_in[3];
    const float* b1 = (const float*)d_in[4];
    const float* W2 = (const float*)d_in[5];
    const float* b2 = (const float*)d_in[6];
    float* out = (float*)d_out;   // [8192*1024] out, then [1] aux

    char* ws = (char*)d_ws;
    int*   expert_count = (int*)(ws + 0);
    float* prob_sum     = (float*)(ws + 32);
    int*   padded_count = (int*)(ws + 64);
    int*   poffsets     = (int*)(ws + 96);
    int*   list_token   = (int*)(ws + 256);                 // 256 KiB
    float* list_w       = (float*)(ws + 256 + 262144);      // 256 KiB
    int*   tok_e        = (int*)(ws + 524544);              // 64 KiB
    int*   tok_q        = (int*)(ws + 524544 + 65536);      // 64 KiB
    float* tok_w        = (float*)(ws + 524544 + 131072);   // 64 KiB

    // Layout: HDR | Hb (144.7M) | W2c (67.1M) | Xg (36.2M) | W1c (67.1M);
    // Og (fp32, 72.4M) aliases Xg+W1c (both dead after gemm1). Total ~316.1 MB.
    const size_t HDR    = 1048576;
    const size_t OFF_HB = HDR;
    const size_t OFF_W2 = OFF_HB + (size_t)MAXRA * DFF * 2;
    const size_t OFF_XG = OFF_W2 + (size_t)NE * DM * DFF * 2;
    const size_t OFF_W1 = OFF_XG + (size_t)MAXRA * DM * 2;
    u16*   Hb  = (u16*)(ws + OFF_HB);
    u16*   W2c = (u16*)(ws + OFF_W2);
    u16*   Xg  = (u16*)(ws + OFF_XG);
    u16*   W1c = (u16*)(ws + OFF_W1);
    float* Og  = (float*)(ws + OFF_XG);

    hipMemsetAsync(ws, 0, 64, stream);
    router_k<<<TT / RTOK, 256, 0, stream>>>(x, Wr, br, expert_count, prob_sum, list_token, list_w,
                                            tok_e, tok_q, tok_w);
    scan_aux_k<<<1, 64, 0, stream>>>(expert_count, prob_sum, padded_count, poffsets,
                                     out + (size_t)TT * DM);
    gather_k<<<dim3(1024, 8), 256, 0, stream>>>(x, list_token, expert_count, padded_count, poffsets, Xg);

    // W1[e][k<1024][j<4096] -> W1c[e][j][k] ; W2[e][k<4096][j<1024] -> W2c[e][j][k]
    convt_k<<<dim3(16, 64, 8), 256, 0, stream>>>(W1, W1c, DFF, 1024, (long)DM * DFF);
    convt_k<<<dim3(64, 16, 8), 256, 0, stream>>>(W2, W2c, DM, 4096, (long)DM * DFF);

    // 256x128 tiles: gemm1 cb=32 (N=4096), gemm2 cb=8 (N=1024); rb up to 33 (8448 max rows/expert)
    gemm1_k<<<dim3(32, 33, 8), 256, 0, stream>>>(Xg, W1c, b1, padded_count, poffsets, Hb);
    gemm2_k<<<dim3(8, 33, 8), 256, 0, stream>>>(Hb, W2c, padded_count, poffsets, Og);
    combine_k<<<TT / 4, 256, 0, stream>>>(Og, b2, tok_e, tok_q, tok_w, poffsets, out);
}

// Round 9
// 607.139 us; speedup vs baseline: 1.1124x; 1.1124x over previous
//
#include <hip/hip_runtime.h>

#define DM     1024
#define DFF    4096
#define NE     8
#define TT     8192
#define CAP    8192
#define RTOK   32
#define MAXRA  17664

typedef __bf16 bf16x8 __attribute__((ext_vector_type(8)));
typedef float  f32x4  __attribute__((ext_vector_type(4)));
typedef unsigned short u16;
typedef unsigned int   u32;

__device__ __forceinline__ u16 f2bf(float f) {
    u32 u = __builtin_bit_cast(u32, f);
    u += 0x7fffu + ((u >> 16) & 1u);   // round-to-nearest-even
    return (u16)(u >> 16);
}

__device__ __forceinline__ void gload_lds16(const void* g, void* l) {
    __builtin_amdgcn_global_load_lds(
        (const __attribute__((address_space(1))) void*)g,
        (__attribute__((address_space(3))) void*)l,
        16, 0, 0);
}

// ---------------- router: block-aggregated top-2 routing ----------------
__global__ __launch_bounds__(256) void router_k(
    const float* __restrict__ x, const float* __restrict__ Wr, const float* __restrict__ br,
    int* __restrict__ expert_count, float* __restrict__ prob_sum,
    int* __restrict__ list_token, float* __restrict__ list_w,
    int* __restrict__ tok_e, int* __restrict__ tok_q, float* __restrict__ tok_w)
{
    __shared__ float wrT[NE][DM];
    __shared__ float ps[NE];
    __shared__ int   lcount[NE];
    __shared__ int   lbase[NE];
    __shared__ int   lexp[RTOK * 2];
    __shared__ float lw[RTOK * 2];
    __shared__ int   lslot[RTOK * 2];

    int tid = threadIdx.x;
    if (tid < NE) { ps[tid] = 0.f; lcount[tid] = 0; }
#pragma unroll
    for (int it = 0; it < 8; ++it) {
        int f = tid * 4 + it * 1024;
        float4 v = *reinterpret_cast<const float4*>(Wr + f);
        int e0 = f & 7, k = f >> 3;
        wrT[e0][k] = v.x; wrT[e0 + 1][k] = v.y; wrT[e0 + 2][k] = v.z; wrT[e0 + 3][k] = v.w;
    }
    __syncthreads();

    int w = tid >> 6, l = tid & 63;
    for (int j = 0; j < RTOK / 4; ++j) {
        int ti = w * (RTOK / 4) + j;
        int token = blockIdx.x * RTOK + ti;
        const float* xr = x + (size_t)token * DM;
        float acc[NE];
#pragma unroll
        for (int e = 0; e < NE; ++e) acc[e] = 0.f;
#pragma unroll
        for (int i = 0; i < 4; ++i) {
            float4 xv = *reinterpret_cast<const float4*>(xr + i * 256 + l * 4);
#pragma unroll
            for (int e = 0; e < NE; ++e) {
                float4 wv = *reinterpret_cast<const float4*>(&wrT[e][i * 256 + l * 4]);
                acc[e] += xv.x * wv.x + xv.y * wv.y + xv.z * wv.z + xv.w * wv.w;
            }
        }
#pragma unroll
        for (int off = 32; off >= 1; off >>= 1) {
#pragma unroll
            for (int e = 0; e < NE; ++e) acc[e] += __shfl_xor(acc[e], off);
        }
        if (l == 0) {
            float li[NE], m = -1e30f;
#pragma unroll
            for (int e = 0; e < NE; ++e) { li[e] = (acc[e] + br[e]) * (1.0f / 0.7f); m = fmaxf(m, li[e]); }
            float p[NE], s = 0.f;
#pragma unroll
            for (int e = 0; e < NE; ++e) { p[e] = __expf(li[e] - m); s += p[e]; }
            float inv = 1.f / s;
#pragma unroll
            for (int e = 0; e < NE; ++e) { p[e] *= inv; atomicAdd(&ps[e], p[e]); }
            float v1 = -1.f, v2 = -1.f; int e1 = 0, e2 = 0;
#pragma unroll
            for (int e = 0; e < NE; ++e) {   // ascending scan: ties keep lower index (top_k semantics)
                float pe = p[e];
                if (pe > v1)      { v2 = v1; e2 = e1; v1 = pe; e1 = e; }
                else if (pe > v2) { v2 = pe; e2 = e; }
            }
            float denom = v1 + v2 + 1e-6f;
            lexp[2 * ti]     = e1; lw[2 * ti]     = v1 / denom; lslot[2 * ti]     = atomicAdd(&lcount[e1], 1);
            lexp[2 * ti + 1] = e2; lw[2 * ti + 1] = v2 / denom; lslot[2 * ti + 1] = atomicAdd(&lcount[e2], 1);
        }
    }
    __syncthreads();
    if (tid < NE) {
        lbase[tid] = atomicAdd(&expert_count[tid], lcount[tid]);
        atomicAdd(&prob_sum[tid], ps[tid]);
    }
    __syncthreads();
    if (tid < RTOK * 2) {
        int e = lexp[tid];
        int q = lbase[e] + lslot[tid];
        int token = blockIdx.x * RTOK + (tid >> 1);
        list_token[e * CAP + q] = token;
        list_w[e * CAP + q] = lw[tid];
        int slot = token * 2 + (tid & 1);
        tok_e[slot] = e; tok_q[slot] = q; tok_w[slot] = lw[tid];
    }
}

// ---------------- scan: padded offsets (to 128) + aux loss ----------------
__global__ void scan_aux_k(const int* __restrict__ expert_count, const float* __restrict__ prob_sum,
                           int* __restrict__ padded_count, int* __restrict__ poffsets,
                           float* __restrict__ aux_out)
{
    if (threadIdx.x == 0 && blockIdx.x == 0) {
        int off = 0; float aux = 0.f;
        for (int e = 0; e < NE; ++e) {
            int c = expert_count[e];
            int pc = (c + 127) / 128 * 128;
            poffsets[e] = off; padded_count[e] = pc; off += pc;
            aux += ((float)c / (float)TT) * (prob_sum[e] / (float)TT);
        }
        aux_out[0] = aux * (float)NE;
    }
}

// ---------------- gather routed x rows -> bf16 Xg ----------------
__global__ __launch_bounds__(256) void gather_k(
    const float* __restrict__ x, const int* __restrict__ list_token,
    const int* __restrict__ expert_count, const int* __restrict__ padded_count,
    const int* __restrict__ poffsets, u16* __restrict__ Xg)
{
    int e = blockIdx.y;
    int p0 = blockIdx.x * 8;
    if (p0 >= padded_count[e]) return;
    int tid = threadIdx.x;
    int rr = tid >> 5, cl = tid & 31;
    int p = p0 + rr;
    int g = poffsets[e] + p;
    u16* dst = Xg + (size_t)g * DM;
    bool valid = p < expert_count[e];
    int tok = valid ? list_token[e * CAP + p] : 0;
    const float* src = x + (size_t)tok * DM;
#pragma unroll
    for (int i = 0; i < 4; ++i) {
        int c0 = cl * 8 + i * 256;
        uint4 v;
        if (valid) {
            float4 f0 = *reinterpret_cast<const float4*>(src + c0);
            float4 f1 = *reinterpret_cast<const float4*>(src + c0 + 4);
            v.x = f2bf(f0.x) | ((u32)f2bf(f0.y) << 16);
            v.y = f2bf(f0.z) | ((u32)f2bf(f0.w) << 16);
            v.z = f2bf(f1.x) | ((u32)f2bf(f1.y) << 16);
            v.w = f2bf(f1.z) | ((u32)f2bf(f1.w) << 16);
        } else {
            v.x = 0; v.y = 0; v.z = 0; v.w = 0;
        }
        *reinterpret_cast<uint4*>(dst + c0) = v;
    }
}

// ---------------- transpose + fp32->bf16: src[e][k*rs + j] -> dst[e][j*Ktot + k] ----------------
__global__ __launch_bounds__(256) void convt_k(
    const float* __restrict__ src, u16* __restrict__ dst, int rs, int Ktot, long dstEStride)
{
    __shared__ float tile[64][65];
    int e = blockIdx.z;
    int k0 = blockIdx.x * 64, j0 = blockIdx.y * 64;
    const float* s = src + (size_t)e * 4194304;
    int tid = threadIdx.x;
    {
        int jj = (tid & 15) * 4, kb = tid >> 4;
#pragma unroll
        for (int i = 0; i < 4; ++i) {
            int k = kb + i * 16;
            float4 v = *reinterpret_cast<const float4*>(s + (size_t)(k0 + k) * rs + j0 + jj);
            tile[k][jj] = v.x; tile[k][jj + 1] = v.y; tile[k][jj + 2] = v.z; tile[k][jj + 3] = v.w;
        }
    }
    __syncthreads();
    {
        int kk = (tid & 15) * 4, jb = tid >> 4;
        u16* d = dst + (size_t)e * dstEStride;
#pragma unroll
        for (int i = 0; i < 4; ++i) {
            int j = jb + i * 16;
            uint2 q;
            q.x = f2bf(tile[kk][j])     | ((u32)f2bf(tile[kk + 1][j]) << 16);
            q.y = f2bf(tile[kk + 2][j]) | ((u32)f2bf(tile[kk + 3][j]) << 16);
            *reinterpret_cast<uint2*>(d + (size_t)(j0 + j) * Ktot + k0 + kk) = q;
        }
    }
}

// ================= 256x256 8-wave GEMM, m201-faithful 4-phase/K-tile schedule =================
// 16x16x32 MFMA (0-conflict read pattern, proven R2-R7). Half-split row maps:
//   A row = mh*128 + wm*64 + mi*16 + lane16 ; B row = nh*128 + wn*32 + ni*16 + lane16
// => hA0 read only in p0 (regs reused p1), hB0 only p0, hB1 only p1, hA1 only p2.
// Stage slots (1 half-tile/phase): p0:(T+1).hA1  p1:(T+2).hA0  p2:(T+2).hB0  p3:(T+2).hB1
// vmcnt(6) at tile END before closing barrier (join makes per-wave count chip-wide safe).
// LDS 128KB: A dbuf 0/32K, B dbuf 64K/96K; 16KB per half-tile; swizzle slot=row*8+(c8^(row&7)).

__device__ __forceinline__ void stage_half256(const u16* __restrict__ rows, long lda, int kt, char* dst) {
    int tid = threadIdx.x, wid = tid >> 6, l = tid & 63;
#pragma unroll
    for (int i = 0; i < 2; ++i) {
        int sbase = i * 512 + wid * 64;
        int sl = sbase + l;
        int row = sl >> 3;
        int c8 = (sl & 7) ^ (row & 7);
        gload_lds16(rows + (size_t)row * lda + kt * 64 + c8 * 8, dst + sbase * 16);
    }
}

__device__ __forceinline__ void ld_afr(const char* Ahalf, int wm, int lane16, int hi, bf16x8 afr[4][2]) {
#pragma unroll
    for (int kk = 0; kk < 2; ++kk)
#pragma unroll
        for (int mi = 0; mi < 4; ++mi) {
            int rowin = wm * 64 + mi * 16 + lane16;
            int ch = (kk * 4 + hi) ^ (rowin & 7);
            afr[mi][kk] = *reinterpret_cast<const bf16x8*>(Ahalf + (rowin * 8 + ch) * 16);
        }
}
__device__ __forceinline__ void ld_bfr(const char* Bhalf, int wn, int lane16, int hi, bf16x8 bfr[2][2]) {
#pragma unroll
    for (int kk = 0; kk < 2; ++kk)
#pragma unroll
        for (int ni = 0; ni < 2; ++ni) {
            int rowin = wn * 32 + ni * 16 + lane16;
            int ch = (kk * 4 + hi) ^ (rowin & 7);
            bfr[ni][kk] = *reinterpret_cast<const bf16x8*>(Bhalf + (rowin * 8 + ch) * 16);
        }
}

#define MFMA_QUAD(AOFF, BSEL, BOFF)                                                     \
    __builtin_amdgcn_s_setprio(1);                                                      \
    _Pragma("unroll")                                                                   \
    for (int kk = 0; kk < 2; ++kk)                                                      \
    _Pragma("unroll")                                                                   \
    for (int mi = 0; mi < 4; ++mi)                                                      \
    _Pragma("unroll")                                                                   \
    for (int ni = 0; ni < 2; ++ni)                                                      \
        acc[(AOFF) + mi][(BOFF) + ni] = __builtin_amdgcn_mfma_f32_16x16x32_bf16(        \
            afr[mi][kk], bfr[BSEL][ni][kk], acc[(AOFF) + mi][(BOFF) + ni], 0, 0, 0);    \
    __builtin_amdgcn_s_setprio(0);

__device__ __forceinline__ void gemm_8p(
    const u16* __restrict__ A, long lda, const u16* __restrict__ B, long ldb,
    int nkt, char* smem, f32x4 acc[8][4])
{
    int tid = threadIdx.x, l = tid & 63, lane16 = l & 15, hi = l >> 4;
    int wid = tid >> 6, wm = wid >> 2, wn = wid & 3;   // 2M x 4N waves

    // prologue order: 0.hA0, 0.hB0, 0.hB1, 0.hA1, 1.hA0, 1.hB0, 1.hB1  (7 half-tiles)
    {
        stage_half256(A,                     lda, 0, smem);
        stage_half256(B,                     ldb, 0, smem + 65536);
        stage_half256(B + (size_t)128 * ldb, ldb, 0, smem + 65536 + 16384);
        stage_half256(A + (size_t)128 * lda, lda, 0, smem + 16384);
        if (nkt > 1) {
            stage_half256(A,                     lda, 1, smem + 32768);
            stage_half256(B,                     ldb, 1, smem + 98304);
            stage_half256(B + (size_t)128 * ldb, ldb, 1, smem + 98304 + 16384);
        }
    }
    if (nkt > 1) asm volatile("s_waitcnt vmcnt(6)" ::: "memory");
    else         asm volatile("s_waitcnt vmcnt(0)" ::: "memory");
    __builtin_amdgcn_s_barrier();

    for (int T = 0; T < nkt; ++T) {
        const char* Ac = smem + (T & 1) * 32768;
        const char* Bc = smem + 65536 + (T & 1) * 32768;
        char* An = smem + ((T + 1) & 1) * 32768;          // buf of T+1 / T+... by parity
        char* Bn = smem + 65536 + ((T + 1) & 1) * 32768;
        char* Ac2 = smem + (T & 1) * 32768;               // buf of T+2 (= parity of T)
        char* Bc2 = smem + 65536 + (T & 1) * 32768;
        bf16x8 afr[4][2], bfr[2][2][2];

        // ---- p0 (m0,n0): read A(m0)+B(n0); stage (T+1).hA1
        ld_afr(Ac, wm, lane16, hi, afr);
        ld_bfr(Bc, wn, lane16, hi, bfr[0]);
        if (T + 1 < nkt) stage_half256(A + (size_t)128 * lda, lda, T + 1, An + 16384);
        asm volatile("s_waitcnt lgkmcnt(8)" ::: "memory");
        __builtin_amdgcn_s_barrier();
        asm volatile("s_waitcnt lgkmcnt(0)" ::: "memory");
        __builtin_amdgcn_sched_barrier(0);
        MFMA_QUAD(0, 0, 0)
        __builtin_amdgcn_s_barrier();

        // ---- p1 (m0,n1): read B(n1); stage (T+2).hA0
        ld_bfr(Bc + 16384, wn, lane16, hi, bfr[1]);
        if (T + 2 < nkt) stage_half256(A, lda, T + 2, Ac2);
        __builtin_amdgcn_s_barrier();
        asm volatile("s_waitcnt lgkmcnt(0)" ::: "memory");
        __builtin_amdgcn_sched_barrier(0);
        MFMA_QUAD(0, 1, 2)
        __builtin_amdgcn_s_barrier();

        // ---- p2 (m1,n0): read A(m1); stage (T+2).hB0
        ld_afr(Ac + 16384, wm, lane16, hi, afr);
        if (T + 2 < nkt) stage_half256(B, ldb, T + 2, Bc2);
        __builtin_amdgcn_s_barrier();
        asm volatile("s_waitcnt lgkmcnt(0)" ::: "memory");
        __builtin_amdgcn_sched_barrier(0);
        MFMA_QUAD(4, 0, 0)
        __builtin_amdgcn_s_barrier();

        // ---- p3 (m1,n1): no reads; stage (T+2).hB1
        if (T + 2 < nkt) stage_half256(B + (size_t)128 * ldb, ldb, T + 2, Bc2 + 16384);
        __builtin_amdgcn_s_barrier();
        MFMA_QUAD(4, 1, 2)
        // tile-end: counted vmcnt guard for tile T+1, then joining barrier
        if (T + 1 < nkt) {
            if (T + 2 < nkt) asm volatile("s_waitcnt vmcnt(6)" ::: "memory");
            else             asm volatile("s_waitcnt vmcnt(0)" ::: "memory");
        }
        __builtin_amdgcn_s_barrier();
        (void)Bn;
    }
}

// ---------------- GEMM1: H = silu(Xg @ W1c + b1), bf16, N=4096, K=1024 ----------------
__global__ __launch_bounds__(512, 2) void gemm1_k(
    const u16* __restrict__ Xg, const u16* __restrict__ W1c, const float* __restrict__ b1,
    const int* __restrict__ padded_count, const int* __restrict__ poffsets,
    u16* __restrict__ H)
{
    __shared__ char smem[131072];
    int cb = blockIdx.x, rb = blockIdx.y, e = blockIdx.z;
    int pc = padded_count[e];
    if (rb * 256 >= pc) return;
    int row0 = poffsets[e] + rb * 256;
    const u16* Arows = Xg + (size_t)row0 * 1024;
    const u16* Brows = W1c + (size_t)e * DFF * 1024 + (size_t)cb * 256 * 1024;
    f32x4 acc[8][4];
#pragma unroll
    for (int i = 0; i < 8; ++i)
#pragma unroll
        for (int j = 0; j < 4; ++j) { acc[i][j][0]=0.f; acc[i][j][1]=0.f; acc[i][j][2]=0.f; acc[i][j][3]=0.f; }
    gemm_8p(Arows, 1024, Brows, 1024, 16, smem, acc);

    int tid = threadIdx.x, l = tid & 63, lane16 = l & 15, hi = l >> 4;
    int wid = tid >> 6, wm = wid >> 2, wn = wid & 3;
    const float* b1e = b1 + (size_t)e * DFF;
#pragma unroll
    for (int a = 0; a < 8; ++a) {
        int mh = a >> 2, mi = a & 3;
#pragma unroll
        for (int b = 0; b < 4; ++b) {
            int nh = b >> 1, ni = b & 1;
            int col = cb * 256 + nh * 128 + wn * 32 + ni * 16 + lane16;
            float bv = b1e[col];
#pragma unroll
            for (int r = 0; r < 4; ++r) {
                int rl = mh * 128 + wm * 64 + mi * 16 + hi * 4 + r;
                int p = rb * 256 + rl;
                if (p < pc) {
                    float z = acc[a][b][r] + bv;
                    H[(size_t)(row0 + rl) * DFF + col] = f2bf(z / (1.f + __expf(-z)));
                }
            }
        }
    }
}

// ---------------- GEMM2: Og[row] = Hb @ W2c, fp32, N=1024, K=4096 ----------------
__global__ __launch_bounds__(512, 2) void gemm2_k(
    const u16* __restrict__ Hb, const u16* __restrict__ W2c,
    const int* __restrict__ padded_count, const int* __restrict__ poffsets,
    float* __restrict__ Og)
{
    __shared__ char smem[131072];
    int cb = blockIdx.x, rb = blockIdx.y, e = blockIdx.z;
    int pc = padded_count[e];
    if (rb * 256 >= pc) return;
    int row0 = poffsets[e] + rb * 256;
    const u16* Arows = Hb + (size_t)row0 * DFF;
    const u16* Brows = W2c + (size_t)e * DM * DFF + (size_t)cb * 256 * DFF;
    f32x4 acc[8][4];
#pragma unroll
    for (int i = 0; i < 8; ++i)
#pragma unroll
        for (int j = 0; j < 4; ++j) { acc[i][j][0]=0.f; acc[i][j][1]=0.f; acc[i][j][2]=0.f; acc[i][j][3]=0.f; }
    gemm_8p(Arows, DFF, Brows, DFF, 64, smem, acc);

    int tid = threadIdx.x, l = tid & 63, lane16 = l & 15, hi = l >> 4;
    int wid = tid >> 6, wm = wid >> 2, wn = wid & 3;
#pragma unroll
    for (int a = 0; a < 8; ++a) {
        int mh = a >> 2, mi = a & 3;
#pragma unroll
        for (int r = 0; r < 4; ++r) {
            int rl = mh * 128 + wm * 64 + mi * 16 + hi * 4 + r;
            int p = rb * 256 + rl;
            if (p < pc) {
                float* orow = Og + (size_t)(row0 + rl) * DM;
#pragma unroll
                for (int b = 0; b < 4; ++b) {
                    int nh = b >> 1, ni = b & 1;
                    int col = cb * 256 + nh * 128 + wn * 32 + ni * 16 + lane16;
                    orow[col] = acc[a][b][r];
                }
            }
        }
    }
}

// ---------------- combine: out[t] = sum_r w_r * (Og[row_r] + b2[e_r]) ----------------
__global__ __launch_bounds__(256) void combine_k(
    const float* __restrict__ Og, const float* __restrict__ b2,
    const int* __restrict__ tok_e, const int* __restrict__ tok_q, const float* __restrict__ tok_w,
    const int* __restrict__ poffsets, float* __restrict__ out)
{
    int t = blockIdx.x * 4 + (threadIdx.x >> 6);
    int l = threadIdx.x & 63;
    int e0 = tok_e[t * 2], q0 = tok_q[t * 2];
    int e1 = tok_e[t * 2 + 1], q1 = tok_q[t * 2 + 1];
    float w0 = tok_w[t * 2], w1 = tok_w[t * 2 + 1];
    const float* r0 = Og + (size_t)(poffsets[e0] + q0) * DM;
    const float* r1 = Og + (size_t)(poffsets[e1] + q1) * DM;
    const float* bb0 = b2 + (size_t)e0 * DM;
    const float* bb1 = b2 + (size_t)e1 * DM;
    float* o = out + (size_t)t * DM;
#pragma unroll
    for (int i = 0; i < 4; ++i) {
        int c = l * 4 + i * 256;
        float4 a = *reinterpret_cast<const float4*>(r0 + c);
        float4 b = *reinterpret_cast<const float4*>(r1 + c);
        float4 p = *reinterpret_cast<const float4*>(bb0 + c);
        float4 q = *reinterpret_cast<const float4*>(bb1 + c);
        float4 res;
        res.x = w0 * (a.x + p.x) + w1 * (b.x + q.x);
        res.y = w0 * (a.y + p.y) + w1 * (b.y + q.y);
        res.z = w0 * (a.z + p.z) + w1 * (b.z + q.z);
        res.w = w0 * (a.w + p.w) + w1 * (b.w + q.w);
        *reinterpret_cast<float4*>(o + c) = res;
    }
}

extern "C" void kernel_launch(void* const* d_in, const int* in_sizes, int n_in,
                              void* d_out, int out_size, void* d_ws, size_t ws_size,
                              hipStream_t stream) {
    (void)in_sizes; (void)n_in; (void)out_size; (void)ws_size;
    const float* x  = (const float*)d_in[0];
    const float* Wr = (const float*)d_in[1];
    const float* br = (const float*)d_in[2];
    const float* W1 = (const float*)d_in[3];
    const float* b1 = (const float*)d_in[4];
    const float* W2 = (const float*)d_in[5];
    const float* b2 = (const float*)d_in[6];
    float* out = (float*)d_out;   // [8192*1024] out, then [1] aux

    char* ws = (char*)d_ws;
    int*   expert_count = (int*)(ws + 0);
    float* prob_sum     = (float*)(ws + 32);
    int*   padded_count = (int*)(ws + 64);
    int*   poffsets     = (int*)(ws + 96);
    int*   list_token   = (int*)(ws + 256);                 // 256 KiB
    float* list_w       = (float*)(ws + 256 + 262144);      // 256 KiB
    int*   tok_e        = (int*)(ws + 524544);              // 64 KiB
    int*   tok_q        = (int*)(ws + 524544 + 65536);      // 64 KiB
    float* tok_w        = (float*)(ws + 524544 + 131072);   // 64 KiB

    // Layout: HDR | Hb (144.7M) | W2c (67.1M) | Xg (36.2M) | W1c (67.1M);
    // Og (fp32, 72.4M) aliases Xg+W1c (both dead after gemm1). Total ~316.1 MB.
    const size_t HDR    = 1048576;
    const size_t OFF_HB = HDR;
    const size_t OFF_W2 = OFF_HB + (size_t)MAXRA * DFF * 2;
    const size_t OFF_XG = OFF_W2 + (size_t)NE * DM * DFF * 2;
    const size_t OFF_W1 = OFF_XG + (size_t)MAXRA * DM * 2;
    u16*   Hb  = (u16*)(ws + OFF_HB);
    u16*   W2c = (u16*)(ws + OFF_W2);
    u16*   Xg  = (u16*)(ws + OFF_XG);
    u16*   W1c = (u16*)(ws + OFF_W1);
    float* Og  = (float*)(ws + OFF_XG);

    hipMemsetAsync(ws, 0, 64, stream);
    router_k<<<TT / RTOK, 256, 0, stream>>>(x, Wr, br, expert_count, prob_sum, list_token, list_w,
                                            tok_e, tok_q, tok_w);
    scan_aux_k<<<1, 64, 0, stream>>>(expert_count, prob_sum, padded_count, poffsets,
                                     out + (size_t)TT * DM);
    gather_k<<<dim3(1024, 8), 256, 0, stream>>>(x, list_token, expert_count, padded_count, poffsets, Xg);

    // W1[e][k<1024][j<4096] -> W1c[e][j][k] ; W2[e][k<4096][j<1024] -> W2c[e][j][k]
    convt_k<<<dim3(16, 64, 8), 256, 0, stream>>>(W1, W1c, DFF, 1024, (long)DM * DFF);
    convt_k<<<dim3(64, 16, 8), 256, 0, stream>>>(W2, W2c, DM, 4096, (long)DM * DFF);

    gemm1_k<<<dim3(16, 32, 8), 512, 0, stream>>>(Xg, W1c, b1, padded_count, poffsets, Hb);
    gemm2_k<<<dim3(4, 32, 8), 512, 0, stream>>>(Hb, W2c, padded_count, poffsets, Og);
    combine_k<<<TT / 4, 256, 0, stream>>>(Og, b2, tok_e, tok_q, tok_w, poffsets, out);
}

// Round 10
// 525.928 us; speedup vs baseline: 1.2842x; 1.1544x over previous
//
#include <hip/hip_runtime.h>

#define DM     1024
#define DFF    4096
#define NE     8
#define TT     8192
#define CAP    8192
#define RTOK   32
#define MAXRA  17664

typedef __bf16 bf16x8 __attribute__((ext_vector_type(8)));
typedef float  f32x4  __attribute__((ext_vector_type(4)));
typedef unsigned short u16;
typedef unsigned int   u32;

__device__ __forceinline__ u16 f2bf(float f) {
    u32 u = __builtin_bit_cast(u32, f);
    u += 0x7fffu + ((u >> 16) & 1u);   // round-to-nearest-even
    return (u16)(u >> 16);
}

__device__ __forceinline__ float bf2f(u16 h) {
    u32 u = ((u32)h) << 16;
    return __builtin_bit_cast(float, u);
}

__device__ __forceinline__ void gload_lds16(const void* g, void* l) {
    __builtin_amdgcn_global_load_lds(
        (const __attribute__((address_space(1))) void*)g,
        (__attribute__((address_space(3))) void*)l,
        16, 0, 0);
}

// ---------------- router: block-aggregated top-2 routing ----------------
__global__ __launch_bounds__(256) void router_k(
    const float* __restrict__ x, const float* __restrict__ Wr, const float* __restrict__ br,
    int* __restrict__ expert_count, float* __restrict__ prob_sum,
    int* __restrict__ list_token, float* __restrict__ list_w,
    int* __restrict__ tok_e, int* __restrict__ tok_q, float* __restrict__ tok_w)
{
    __shared__ float wrT[NE][DM];
    __shared__ float ps[NE];
    __shared__ int   lcount[NE];
    __shared__ int   lbase[NE];
    __shared__ int   lexp[RTOK * 2];
    __shared__ float lw[RTOK * 2];
    __shared__ int   lslot[RTOK * 2];

    int tid = threadIdx.x;
    if (tid < NE) { ps[tid] = 0.f; lcount[tid] = 0; }
#pragma unroll
    for (int it = 0; it < 8; ++it) {
        int f = tid * 4 + it * 1024;
        float4 v = *reinterpret_cast<const float4*>(Wr + f);
        int e0 = f & 7, k = f >> 3;
        wrT[e0][k] = v.x; wrT[e0 + 1][k] = v.y; wrT[e0 + 2][k] = v.z; wrT[e0 + 3][k] = v.w;
    }
    __syncthreads();

    int w = tid >> 6, l = tid & 63;
    for (int j = 0; j < RTOK / 4; ++j) {
        int ti = w * (RTOK / 4) + j;
        int token = blockIdx.x * RTOK + ti;
        const float* xr = x + (size_t)token * DM;
        float acc[NE];
#pragma unroll
        for (int e = 0; e < NE; ++e) acc[e] = 0.f;
#pragma unroll
        for (int i = 0; i < 4; ++i) {
            float4 xv = *reinterpret_cast<const float4*>(xr + i * 256 + l * 4);
#pragma unroll
            for (int e = 0; e < NE; ++e) {
                float4 wv = *reinterpret_cast<const float4*>(&wrT[e][i * 256 + l * 4]);
                acc[e] += xv.x * wv.x + xv.y * wv.y + xv.z * wv.z + xv.w * wv.w;
            }
        }
#pragma unroll
        for (int off = 32; off >= 1; off >>= 1) {
#pragma unroll
            for (int e = 0; e < NE; ++e) acc[e] += __shfl_xor(acc[e], off);
        }
        if (l == 0) {
            float li[NE], m = -1e30f;
#pragma unroll
            for (int e = 0; e < NE; ++e) { li[e] = (acc[e] + br[e]) * (1.0f / 0.7f); m = fmaxf(m, li[e]); }
            float p[NE], s = 0.f;
#pragma unroll
            for (int e = 0; e < NE; ++e) { p[e] = __expf(li[e] - m); s += p[e]; }
            float inv = 1.f / s;
#pragma unroll
            for (int e = 0; e < NE; ++e) { p[e] *= inv; atomicAdd(&ps[e], p[e]); }
            float v1 = -1.f, v2 = -1.f; int e1 = 0, e2 = 0;
#pragma unroll
            for (int e = 0; e < NE; ++e) {   // ascending scan: ties keep lower index (top_k semantics)
                float pe = p[e];
                if (pe > v1)      { v2 = v1; e2 = e1; v1 = pe; e1 = e; }
                else if (pe > v2) { v2 = pe; e2 = e; }
            }
            float denom = v1 + v2 + 1e-6f;
            lexp[2 * ti]     = e1; lw[2 * ti]     = v1 / denom; lslot[2 * ti]     = atomicAdd(&lcount[e1], 1);
            lexp[2 * ti + 1] = e2; lw[2 * ti + 1] = v2 / denom; lslot[2 * ti + 1] = atomicAdd(&lcount[e2], 1);
        }
    }
    __syncthreads();
    if (tid < NE) {
        lbase[tid] = atomicAdd(&expert_count[tid], lcount[tid]);
        atomicAdd(&prob_sum[tid], ps[tid]);
    }
    __syncthreads();
    if (tid < RTOK * 2) {
        int e = lexp[tid];
        int q = lbase[e] + lslot[tid];
        int token = blockIdx.x * RTOK + (tid >> 1);
        list_token[e * CAP + q] = token;
        list_w[e * CAP + q] = lw[tid];
        int slot = token * 2 + (tid & 1);
        tok_e[slot] = e; tok_q[slot] = q; tok_w[slot] = lw[tid];
    }
}

// ---------------- scan: padded offsets (to 128) + aux loss ----------------
__global__ void scan_aux_k(const int* __restrict__ expert_count, const float* __restrict__ prob_sum,
                           int* __restrict__ padded_count, int* __restrict__ poffsets,
                           float* __restrict__ aux_out)
{
    if (threadIdx.x == 0 && blockIdx.x == 0) {
        int off = 0; float aux = 0.f;
        for (int e = 0; e < NE; ++e) {
            int c = expert_count[e];
            int pc = (c + 127) / 128 * 128;
            poffsets[e] = off; padded_count[e] = pc; off += pc;
            aux += ((float)c / (float)TT) * (prob_sum[e] / (float)TT);
        }
        aux_out[0] = aux * (float)NE;
    }
}

// ---------------- gather routed x rows -> bf16 Xg ----------------
__global__ __launch_bounds__(256) void gather_k(
    const float* __restrict__ x, const int* __restrict__ list_token,
    const int* __restrict__ expert_count, const int* __restrict__ padded_count,
    const int* __restrict__ poffsets, u16* __restrict__ Xg)
{
    int e = blockIdx.y;
    int p0 = blockIdx.x * 8;
    if (p0 >= padded_count[e]) return;
    int tid = threadIdx.x;
    int rr = tid >> 5, cl = tid & 31;
    int p = p0 + rr;
    int g = poffsets[e] + p;
    u16* dst = Xg + (size_t)g * DM;
    bool valid = p < expert_count[e];
    int tok = valid ? list_token[e * CAP + p] : 0;
    const float* src = x + (size_t)tok * DM;
#pragma unroll
    for (int i = 0; i < 4; ++i) {
        int c0 = cl * 8 + i * 256;
        uint4 v;
        if (valid) {
            float4 f0 = *reinterpret_cast<const float4*>(src + c0);
            float4 f1 = *reinterpret_cast<const float4*>(src + c0 + 4);
            v.x = f2bf(f0.x) | ((u32)f2bf(f0.y) << 16);
            v.y = f2bf(f0.z) | ((u32)f2bf(f0.w) << 16);
            v.z = f2bf(f1.x) | ((u32)f2bf(f1.y) << 16);
            v.w = f2bf(f1.z) | ((u32)f2bf(f1.w) << 16);
        } else {
            v.x = 0; v.y = 0; v.z = 0; v.w = 0;
        }
        *reinterpret_cast<uint4*>(dst + c0) = v;
    }
}

// ---------------- transpose + fp32->bf16: src[e][k*rs + j] -> dst[e][j*Ktot + k] ----------------
__global__ __launch_bounds__(256) void convt_k(
    const float* __restrict__ src, u16* __restrict__ dst, int rs, int Ktot, long dstEStride)
{
    __shared__ float tile[64][65];
    int e = blockIdx.z;
    int k0 = blockIdx.x * 64, j0 = blockIdx.y * 64;
    const float* s = src + (size_t)e * 4194304;
    int tid = threadIdx.x;
    {
        int jj = (tid & 15) * 4, kb = tid >> 4;
#pragma unroll
        for (int i = 0; i < 4; ++i) {
            int k = kb + i * 16;
            float4 v = *reinterpret_cast<const float4*>(s + (size_t)(k0 + k) * rs + j0 + jj);
            tile[k][jj] = v.x; tile[k][jj + 1] = v.y; tile[k][jj + 2] = v.z; tile[k][jj + 3] = v.w;
        }
    }
    __syncthreads();
    {
        int kk = (tid & 15) * 4, jb = tid >> 4;
        u16* d = dst + (size_t)e * dstEStride;
#pragma unroll
        for (int i = 0; i < 4; ++i) {
            int j = jb + i * 16;
            uint2 q;
            q.x = f2bf(tile[kk][j])     | ((u32)f2bf(tile[kk + 1][j]) << 16);
            q.y = f2bf(tile[kk + 2][j]) | ((u32)f2bf(tile[kk + 3][j]) << 16);
            *reinterpret_cast<uint2*>(d + (size_t)(j0 + j) * Ktot + k0 + kk) = q;
        }
    }
}

// ---------------- PROVEN 128x128 bf16 GEMM mainloop (single-buffer, gload_lds, 256 thr) ----------------
// 16B chunk slot = row*8 + (c8 ^ (row&7)); staged linearly via pre-swizzled global source
// (both-sides involution; 0 bank conflicts measured R2-R9). This is the m97-class structure:
// gemm1 ~750 TF / gemm2 ~610 TF at these shapes — at the structure's proven shape-ceiling (m102).
__device__ __forceinline__ void stage_tile(const u16* __restrict__ rows, long lda, int kt, char* buf) {
    int tid = threadIdx.x;
    int w = tid >> 6, l = tid & 63;
#pragma unroll
    for (int i = 0; i < 4; ++i) {
        int sbase = i * 256 + w * 64;       // wave-uniform LDS slot base
        int sl = sbase + l;
        int row = sl >> 3;
        int c8 = (sl & 7) ^ (row & 7);
        const u16* src = rows + (size_t)row * lda + kt * 64 + c8 * 8;
        gload_lds16(src, buf + sbase * 16);
    }
}

__device__ __forceinline__ void gemm_main(
    const u16* __restrict__ Arows, long lda,
    const u16* __restrict__ Brows, long ldb,
    int nkt, char* smem, f32x4 acc[4][4])
{
    int tid = threadIdx.x;
    int l = tid & 63, lane16 = l & 15, hi = l >> 4;
    int wm = (tid >> 6) & 1, wn = tid >> 7;

    for (int kt = 0; kt < nkt; ++kt) {
        stage_tile(Arows, lda, kt, smem);
        stage_tile(Brows, ldb, kt, smem + 16384);
        __syncthreads();
        const char* bufA = smem;
        const char* bufB = smem + 16384;
#pragma unroll
        for (int kk = 0; kk < 2; ++kk) {
            bf16x8 af[4], bb[4];
#pragma unroll
            for (int mi = 0; mi < 4; ++mi) {
                int row = wm * 64 + mi * 16 + lane16;
                int ch = (kk * 4 + hi) ^ (row & 7);
                af[mi] = *reinterpret_cast<const bf16x8*>(bufA + (row * 8 + ch) * 16);
            }
#pragma unroll
            for (int ni = 0; ni < 4; ++ni) {
                int row = wn * 64 + ni * 16 + lane16;
                int ch = (kk * 4 + hi) ^ (row & 7);
                bb[ni] = *reinterpret_cast<const bf16x8*>(bufB + (row * 8 + ch) * 16);
            }
#pragma unroll
            for (int mi = 0; mi < 4; ++mi)
#pragma unroll
                for (int ni = 0; ni < 4; ++ni)
                    acc[mi][ni] = __builtin_amdgcn_mfma_f32_16x16x32_bf16(af[mi], bb[ni], acc[mi][ni], 0, 0, 0);
        }
        __syncthreads();
    }
}

// ---------------- GEMM1: H = silu(Xg @ W1c + b1), bf16, N=4096, K=1024 ----------------
// Region-ordered swizzled 1D grid: e (8) x group (8: 8 rb) x rb-in-group (8) x cb (32).
__global__ __launch_bounds__(256, 4) void gemm1_k(
    const u16* __restrict__ Xg, const u16* __restrict__ W1c, const float* __restrict__ b1,
    const int* __restrict__ padded_count, const int* __restrict__ poffsets,
    u16* __restrict__ H)
{
    __shared__ char smem[32768];
    int n = blockIdx.x;
    int e = n >> 11, r11 = n & 2047;
    int g = r11 >> 8;
    int rb = g * 8 + ((r11 >> 5) & 7);
    int cb = r11 & 31;
    if (rb * 128 >= padded_count[e]) return;
    int row0 = poffsets[e] + rb * 128;
    const u16* Arows = Xg + (size_t)row0 * 1024;
    const u16* Brows = W1c + (size_t)e * DFF * 1024 + (size_t)cb * 128 * 1024;
    f32x4 acc[4][4];
#pragma unroll
    for (int i = 0; i < 4; ++i)
#pragma unroll
        for (int j = 0; j < 4; ++j) { acc[i][j][0]=0.f; acc[i][j][1]=0.f; acc[i][j][2]=0.f; acc[i][j][3]=0.f; }
    gemm_main(Arows, 1024, Brows, 1024, 16, smem, acc);

    int tid = threadIdx.x;
    int l = tid & 63, lane16 = l & 15, hi = l >> 4;
    int wm = (tid >> 6) & 1, wn = tid >> 7;
    const float* b1e = b1 + (size_t)e * DFF;
#pragma unroll
    for (int mi = 0; mi < 4; ++mi) {
#pragma unroll
        for (int ni = 0; ni < 4; ++ni) {
            int col = cb * 128 + wn * 64 + ni * 16 + lane16;
            float bv = b1e[col];
#pragma unroll
            for (int r = 0; r < 4; ++r) {
                int grow = row0 + wm * 64 + mi * 16 + hi * 4 + r;
                float z = acc[mi][ni][r] + bv;
                float hval = z / (1.f + __expf(-z));
                H[(size_t)grow * DFF + col] = f2bf(hval);
            }
        }
    }
}

// ---------------- GEMM2: Og[row] = Hb @ W2c (bf16 out), K=4096 ----------------
// Region-ordered swizzled 1D grid: e (8) x group (4: 16 rb) x rb-in-group (16) x cb (8).
__global__ __launch_bounds__(256, 4) void gemm2_k(
    const u16* __restrict__ Hb, const u16* __restrict__ W2c,
    const int* __restrict__ padded_count, const int* __restrict__ poffsets,
    u16* __restrict__ Og)
{
    __shared__ char smem[32768];
    int n = blockIdx.x;
    int e = n >> 9, r9 = n & 511;
    int g = r9 >> 7;
    int rb = g * 16 + ((r9 >> 3) & 15);
    int cb = r9 & 7;
    if (rb * 128 >= padded_count[e]) return;
    int row0 = poffsets[e] + rb * 128;
    const u16* Arows = Hb + (size_t)row0 * DFF;
    const u16* Brows = W2c + (size_t)e * DM * DFF + (size_t)cb * 128 * DFF;
    f32x4 acc[4][4];
#pragma unroll
    for (int i = 0; i < 4; ++i)
#pragma unroll
        for (int j = 0; j < 4; ++j) { acc[i][j][0]=0.f; acc[i][j][1]=0.f; acc[i][j][2]=0.f; acc[i][j][3]=0.f; }
    gemm_main(Arows, DFF, Brows, DFF, 64, smem, acc);

    int tid = threadIdx.x;
    int l = tid & 63, lane16 = l & 15, hi = l >> 4;
    int wm = (tid >> 6) & 1, wn = tid >> 7;
#pragma unroll
    for (int mi = 0; mi < 4; ++mi) {
#pragma unroll
        for (int r = 0; r < 4; ++r) {
            int grow = row0 + wm * 64 + mi * 16 + hi * 4 + r;
            u16* orow = Og + (size_t)grow * DM;
#pragma unroll
            for (int ni = 0; ni < 4; ++ni) {
                int col = cb * 128 + wn * 64 + ni * 16 + lane16;
                orow[col] = f2bf(acc[mi][ni][r]);
            }
        }
    }
}

// ---------------- combine: out[t] = sum_r w_r * (Og[row_r] + b2[e_r]), Og bf16 ----------------
__global__ __launch_bounds__(256) void combine_k(
    const u16* __restrict__ Og, const float* __restrict__ b2,
    const int* __restrict__ tok_e, const int* __restrict__ tok_q, const float* __restrict__ tok_w,
    const int* __restrict__ poffsets, float* __restrict__ out)
{
    int t = blockIdx.x * 4 + (threadIdx.x >> 6);
    int l = threadIdx.x & 63;
    int e0 = tok_e[t * 2], q0 = tok_q[t * 2];
    int e1 = tok_e[t * 2 + 1], q1 = tok_q[t * 2 + 1];
    float w0 = tok_w[t * 2], w1 = tok_w[t * 2 + 1];
    const u16* r0 = Og + (size_t)(poffsets[e0] + q0) * DM;
    const u16* r1 = Og + (size_t)(poffsets[e1] + q1) * DM;
    const float* bb0 = b2 + (size_t)e0 * DM;
    const float* bb1 = b2 + (size_t)e1 * DM;
    float* o = out + (size_t)t * DM;
#pragma unroll
    for (int i = 0; i < 2; ++i) {
        int c = l * 8 + i * 512;
        uint4 a8 = *reinterpret_cast<const uint4*>(r0 + c);
        uint4 b8 = *reinterpret_cast<const uint4*>(r1 + c);
        const u32* au = &a8.x;
        const u32* bu = &b8.x;
        float4 res[2];
#pragma unroll
        for (int h = 0; h < 2; ++h) {
            float4 p = *reinterpret_cast<const float4*>(bb0 + c + h * 4);
            float4 q = *reinterpret_cast<const float4*>(bb1 + c + h * 4);
            float a0 = bf2f((u16)(au[h * 2] & 0xffff)),     a1 = bf2f((u16)(au[h * 2] >> 16));
            float a2 = bf2f((u16)(au[h * 2 + 1] & 0xffff)), a3 = bf2f((u16)(au[h * 2 + 1] >> 16));
            float c0 = bf2f((u16)(bu[h * 2] & 0xffff)),     c1 = bf2f((u16)(bu[h * 2] >> 16));
            float c2 = bf2f((u16)(bu[h * 2 + 1] & 0xffff)), c3 = bf2f((u16)(bu[h * 2 + 1] >> 16));
            res[h].x = w0 * (a0 + p.x) + w1 * (c0 + q.x);
            res[h].y = w0 * (a1 + p.y) + w1 * (c1 + q.y);
            res[h].z = w0 * (a2 + p.z) + w1 * (c2 + q.z);
            res[h].w = w0 * (a3 + p.w) + w1 * (c3 + q.w);
        }
        *reinterpret_cast<float4*>(o + c) = res[0];
        *reinterpret_cast<float4*>(o + c + 4) = res[1];
    }
}

extern "C" void kernel_launch(void* const* d_in, const int* in_sizes, int n_in,
                              void* d_out, int out_size, void* d_ws, size_t ws_size,
                              hipStream_t stream) {
    (void)in_sizes; (void)n_in; (void)out_size; (void)ws_size;
    const float* x  = (const float*)d_in[0];
    const float* Wr = (const float*)d_in[1];
    const float* br = (const float*)d_in[2];
    const float* W1 = (const float*)d_in[3];
    const float* b1 = (const float*)d_in[4];
    const float* W2 = (const float*)d_in[5];
    const float* b2 = (const float*)d_in[6];
    float* out = (float*)d_out;   // [8192*1024] out, then [1] aux

    char* ws = (char*)d_ws;
    int*   expert_count = (int*)(ws + 0);
    float* prob_sum     = (float*)(ws + 32);
    int*   padded_count = (int*)(ws + 64);
    int*   poffsets     = (int*)(ws + 96);
    int*   list_token   = (int*)(ws + 256);                 // 256 KiB
    float* list_w       = (float*)(ws + 256 + 262144);      // 256 KiB
    int*   tok_e        = (int*)(ws + 524544);              // 64 KiB
    int*   tok_q        = (int*)(ws + 524544 + 65536);      // 64 KiB
    float* tok_w        = (float*)(ws + 524544 + 131072);   // 64 KiB

    // Layout: HDR | Hb (144.7M) | W2c (67.1M) | Xg (36.2M) | W1c (67.1M);
    // Og (bf16, 36.2M) aliases Xg (dead after gemm1). Total ~316.1 MB.
    const size_t HDR    = 1048576;
    const size_t OFF_HB = HDR;
    const size_t OFF_W2 = OFF_HB + (size_t)MAXRA * DFF * 2;
    const size_t OFF_XG = OFF_W2 + (size_t)NE * DM * DFF * 2;
    const size_t OFF_W1 = OFF_XG + (size_t)MAXRA * DM * 2;
    u16*   Hb  = (u16*)(ws + OFF_HB);
    u16*   W2c = (u16*)(ws + OFF_W2);
    u16*   Xg  = (u16*)(ws + OFF_XG);
    u16*   W1c = (u16*)(ws + OFF_W1);
    u16*   Og  = (u16*)(ws + OFF_XG);

    hipMemsetAsync(ws, 0, 64, stream);
    router_k<<<TT / RTOK, 256, 0, stream>>>(x, Wr, br, expert_count, prob_sum, list_token, list_w,
                                            tok_e, tok_q, tok_w);
    scan_aux_k<<<1, 64, 0, stream>>>(expert_count, prob_sum, padded_count, poffsets,
                                     out + (size_t)TT * DM);
    gather_k<<<dim3(1024, 8), 256, 0, stream>>>(x, list_token, expert_count, padded_count, poffsets, Xg);

    // W1[e][k<1024][j<4096] -> W1c[e][j][k] ; W2[e][k<4096][j<1024] -> W2c[e][j][k]
    convt_k<<<dim3(16, 64, 8), 256, 0, stream>>>(W1, W1c, DFF, 1024, (long)DM * DFF);
    convt_k<<<dim3(64, 16, 8), 256, 0, stream>>>(W2, W2c, DM, 4096, (long)DM * DFF);

    gemm1_k<<<16384, 256, 0, stream>>>(Xg, W1c, b1, padded_count, poffsets, Hb);
    gemm2_k<<<4096, 256, 0, stream>>>(Hb, W2c, padded_count, poffsets, Og);
    combine_k<<<TT / 4, 256, 0, stream>>>(Og, b2, tok_e, tok_q, tok_w, poffsets, out);
}